// Round 9
// baseline (221.581 us; speedup 1.0000x reference)
//
#include <hip/hip_runtime.h>
#include <hip/hip_bf16.h>

#define B_ 2
#define H_ 8
#define S_ 2048
#define D_ 64
#define R_ 128

typedef __bf16 bf16x8 __attribute__((ext_vector_type(8)));
typedef unsigned short u16x8 __attribute__((ext_vector_type(8)));
typedef float f32x4 __attribute__((ext_vector_type(4)));
typedef unsigned u32x4 __attribute__((ext_vector_type(4)));

__device__ __forceinline__ unsigned short f2bf(float f) {
  union { float f; unsigned u; } x; x.f = f;
  unsigned r = x.u + 0x7fffu + ((x.u >> 16) & 1u);
  return (unsigned short)(r >> 16);
}
__device__ __forceinline__ float bf2f(unsigned short s) {
  union { unsigned u; float f; } x; x.u = ((unsigned)s) << 16;
  return x.f;
}
// packed f32x2 -> bf16x2 (lo = a, hi = b); no builtin on gfx950, inline asm
__device__ __forceinline__ unsigned cvtpk(float a, float b) {
  unsigned r;
  asm("v_cvt_pk_bf16_f32 %0, %1, %2" : "=v"(r) : "v"(a), "v"(b));
  return r;
}

// ---------------- prepass: K/V -> bf16 (V transposed [d][k]); kinfo -> kfix (-1 remapped) ----------------
__launch_bounds__(256)
__global__ void prep_kernel(const float* __restrict__ kg, const float* __restrict__ vg,
                            const int* __restrict__ kinfo,
                            unsigned short* __restrict__ kws, unsigned short* __restrict__ vws,
                            int* __restrict__ kfix) {
  const int kt = blockIdx.x, bh = blockIdx.y, t = threadIdx.x;
  const float* ksrc = kg + ((size_t)bh * S_ + kt * 64) * 64;
  const float* vsrc = vg + ((size_t)bh * S_ + kt * 64) * 64;
  unsigned short* kd = kws + (size_t)(bh * 32 + kt) * 4096;
  unsigned short* vd = vws + (size_t)(bh * 32 + kt) * 4096;
  // K: plain row-major bf16
#pragma unroll
  for (int p = 0; p < 4; ++p) {
    int row = p * 16 + (t >> 4);
    int col = (t & 15) * 4;
    float4 f = *(const float4*)(ksrc + row * 64 + col);
    uint2 u = make_uint2(cvtpk(f.x, f.y), cvtpk(f.z, f.w));
    *(uint2*)(kd + row * 64 + col) = u;
  }
  // V: transposed [d][k] bf16
  int d0 = (t >> 4) * 4, k0 = (t & 15) * 4;
  float L[4][4];
#pragma unroll
  for (int i = 0; i < 4; ++i)
    *(float4*)L[i] = *(const float4*)(vsrc + (k0 + i) * 64 + d0);
#pragma unroll
  for (int j = 0; j < 4; ++j) {
    uint2 u = make_uint2(cvtpk(L[0][j], L[1][j]), cvtpk(L[2][j], L[3][j]));
    *(uint2*)(vd + (d0 + j) * 64 + k0) = u;
  }
  // kinfo fixup (once per element)
  if (bh < B_ && t < 64) {
    int v = kinfo[bh * S_ + kt * 64 + t];
    kfix[bh * S_ + kt * 64 + t] = (v == -1) ? 3 * R_ : v;
  }
}

// ---------------- main: barrier-free flash, K/V fragments straight from L2 ----------------
// 2 waves/block, 32 q-rows/block (16 per wave, one per lane&15). LDS = bias table only.
// Row stride 272 (NOT 258): the qr store loop writes offsets up to rt*16+lr = 271.
#define QRS 272
#define SMEM4 (32 * QRS * 2)  // 17408 B -> 9 blocks/CU

__launch_bounds__(128, 4)
__global__ void relattn4_kernel(const float* __restrict__ qg, const float* __restrict__ rel,
                                const int* __restrict__ qinfo, const int* __restrict__ kfix,
                                const unsigned short* __restrict__ kws,
                                const unsigned short* __restrict__ vws,
                                float* __restrict__ out) {
  extern __shared__ char smem[];
  unsigned short* qr_l = (unsigned short*)smem;  // [32][QRS] bf16, wave-private rows

  const int t = threadIdx.x;
  const int lane = t & 63, w = t >> 6, lr = lane & 15, lg = lane >> 4;
  // XCD-aware swizzle: blocks with lin%8==c (same XCD) cover bh {2c,2c+1} -> 1MB K/V per XCD L2
  const int lin = blockIdx.x;
  const int idx = lin >> 3;
  const int bh = ((lin & 7) << 1) | (idx >> 6);
  const int qb = idx & 63;
  const int b = bh >> 3;
  const float SC = 0.125f * 1.44269504088896340736f;  // 1/sqrt(64)*log2(e)
  const size_t tb = (size_t)bh * 32;

  // ---- Q fragments straight from global (pre-scaled) ----
  bf16x8 qa0, qa1;
  {
    const float* qrow = qg + ((size_t)bh * S_ + qb * 32 + w * 16 + lr) * 64 + 8 * lg;
    float4 a = *(const float4*)(qrow);
    float4 c = *(const float4*)(qrow + 4);
    u32x4 u0 = {cvtpk(a.x * SC, a.y * SC), cvtpk(a.z * SC, a.w * SC),
                cvtpk(c.x * SC, c.y * SC), cvtpk(c.z * SC, c.w * SC)};
    qa0 = __builtin_bit_cast(bf16x8, u0);
    float4 e = *(const float4*)(qrow + 32);
    float4 g = *(const float4*)(qrow + 36);
    u32x4 u1 = {cvtpk(e.x * SC, e.y * SC), cvtpk(e.z * SC, e.w * SC),
                cvtpk(g.x * SC, g.y * SC), cvtpk(g.z * SC, g.w * SC)};
    qa1 = __builtin_bit_cast(bf16x8, u1);
  }
  int qa;
  {
    int qv = qinfo[b * S_ + qb * 32 + w * 16 + lr];
    qa = (qv == -1) ? 2 * R_ : qv;
  }

  // ---- qr = Qsc @ rel^T (32x257) -> LDS (bf16, scaled); wave-private, no barrier needed ----
  const int qr_wb = (w * 16 + 4 * lg) * QRS;
#pragma unroll 1
  for (int rt = 0; rt < 17; ++rt) {
    int r = rt * 16 + lr;
    u32x4 z = {0, 0, 0, 0};
    bf16x8 rb0 = __builtin_bit_cast(bf16x8, z), rb1 = rb0;
    if (r < 257) {
      const float* rp = rel + r * 64 + 8 * lg;
      float4 fa = *(const float4*)(rp);
      float4 fb = *(const float4*)(rp + 4);
      u32x4 ua = {cvtpk(fa.x, fa.y), cvtpk(fa.z, fa.w), cvtpk(fb.x, fb.y), cvtpk(fb.z, fb.w)};
      rb0 = __builtin_bit_cast(bf16x8, ua);
      float4 fc = *(const float4*)(rp + 32);
      float4 fd = *(const float4*)(rp + 36);
      u32x4 uc = {cvtpk(fc.x, fc.y), cvtpk(fc.z, fc.w), cvtpk(fd.x, fd.y), cvtpk(fd.z, fd.w)};
      rb1 = __builtin_bit_cast(bf16x8, uc);
    }
    f32x4 acc = {0.f, 0.f, 0.f, 0.f};
    acc = __builtin_amdgcn_mfma_f32_16x16x32_bf16(qa0, rb0, acc, 0, 0, 0);
    acc = __builtin_amdgcn_mfma_f32_16x16x32_bf16(qa1, rb1, acc, 0, 0, 0);
#pragma unroll
    for (int j = 0; j < 4; ++j)
      qr_l[qr_wb + j * QRS + rt * 16 + lr] = f2bf(acc[j]);
  }

  // ---- flash state ----
  float m_r = -INFINITY, l_r = 0.f;
  f32x4 o_acc[4];
#pragma unroll
  for (int dt = 0; dt < 4; ++dt) o_acc[dt] = (f32x4){0.f, 0.f, 0.f, 0.f};
  const unsigned short* rowptr = qr_l + (w * 16 + lr) * QRS + R_;  // pre-offset by +R
  const int srcb = ((lg & 1) << 5) | lr;

#pragma unroll 1
  for (int kt = 0; kt < 32; ++kt) {
    const unsigned short* kd = kws + (tb + kt) * 4096;
    const unsigned short* vd = vws + (tb + kt) * 4096;

    // ---- S^T = K Q^T, fragments from L2 ----
    f32x4 sfr[4];
    __builtin_amdgcn_s_setprio(1);
#pragma unroll
    for (int st = 0; st < 4; ++st) {
      const unsigned short* kb = kd + (st * 16 + lr) * 64 + 8 * lg;
      bf16x8 kb0 = *(const bf16x8*)(kb);
      bf16x8 kb1 = *(const bf16x8*)(kb + 32);
      f32x4 acc = {0.f, 0.f, 0.f, 0.f};
      acc = __builtin_amdgcn_mfma_f32_16x16x32_bf16(kb0, qa0, acc, 0, 0, 0);
      acc = __builtin_amdgcn_mfma_f32_16x16x32_bf16(kb1, qa1, acc, 0, 0, 0);
      sfr[st] = acc;
    }
    __builtin_amdgcn_s_setprio(0);

    // ---- bias gather (kfix pre-remapped; clamp+gather) ----
    const int* kfb = kfix + b * S_ + kt * 64 + 4 * lg;
    float tv[4][4];
#pragma unroll
    for (int st = 0; st < 4; ++st) {
      int4 ka4 = *(const int4*)(kfb + st * 16);
      const int* kap = &ka4.x;
#pragma unroll
      for (int j = 0; j < 4; ++j) {
        int dm = min(max(kap[j] - qa, -R_), R_);
        tv[st][j] = sfr[st][j] + bf2f(rowptr[dm]);
      }
    }

    // ---- online softmax with defer-max (THR=8) ----
    float mt = tv[0][0];
#pragma unroll
    for (int st = 0; st < 4; ++st)
#pragma unroll
      for (int j = 0; j < 4; ++j) mt = fmaxf(mt, tv[st][j]);
    mt = fmaxf(mt, __shfl_xor(mt, 16));
    mt = fmaxf(mt, __shfl_xor(mt, 32));
    if (!__all(mt - m_r <= 8.f)) {
      float mnew = fmaxf(m_r, mt);
      float sc2 = exp2f(m_r - mnew);
      l_r *= sc2;
#pragma unroll
      for (int dt = 0; dt < 4; ++dt) o_acc[dt] *= sc2;
      m_r = mnew;
    }
    float rs = 0.f;
#pragma unroll
    for (int st = 0; st < 4; ++st)
#pragma unroll
      for (int j = 0; j < 4; ++j) {
        float p = exp2f(tv[st][j] - m_r);
        tv[st][j] = p;
        rs += p;
      }
    rs += __shfl_xor(rs, 16);
    rs += __shfl_xor(rs, 32);
    l_r += rs;

    // ---- pack P (cvt_pk) and redistribute to PV B-frag via shfl ----
    unsigned pk_[4][2];
#pragma unroll
    for (int st = 0; st < 4; ++st) {
      pk_[st][0] = cvtpk(tv[st][0], tv[st][1]);
      pk_[st][1] = cvtpk(tv[st][2], tv[st][3]);
    }
#pragma unroll
    for (int h = 0; h < 2; ++h) {
      unsigned r0, r1, r2, r3;
      {
        unsigned a0 = (unsigned)__shfl((int)pk_[2 * h][0], srcb);
        unsigned b0 = (unsigned)__shfl((int)pk_[2 * h + 1][0], srcb);
        r0 = (lg & 2) ? b0 : a0;
        unsigned a1 = (unsigned)__shfl((int)pk_[2 * h][1], srcb);
        unsigned b1 = (unsigned)__shfl((int)pk_[2 * h + 1][1], srcb);
        r1 = (lg & 2) ? b1 : a1;
        unsigned a2 = (unsigned)__shfl((int)pk_[2 * h][0], srcb + 16);
        unsigned b2 = (unsigned)__shfl((int)pk_[2 * h + 1][0], srcb + 16);
        r2 = (lg & 2) ? b2 : a2;
        unsigned a3 = (unsigned)__shfl((int)pk_[2 * h][1], srcb + 16);
        unsigned b3 = (unsigned)__shfl((int)pk_[2 * h + 1][1], srcb + 16);
        r3 = (lg & 2) ? b3 : a3;
      }
      u32x4 rv = {r0, r1, r2, r3};
      bf16x8 pb = __builtin_bit_cast(bf16x8, rv);
      // ---- O^T += V^T P, V fragments from L2 ----
      __builtin_amdgcn_s_setprio(1);
#pragma unroll
      for (int dt = 0; dt < 4; ++dt) {
        const unsigned short* vb = vd + (dt * 16 + lr) * 64 + h * 32 + 8 * lg;
        bf16x8 va = *(const bf16x8*)(vb);
        o_acc[dt] = __builtin_amdgcn_mfma_f32_16x16x32_bf16(va, pb, o_acc[dt], 0, 0, 0);
      }
      __builtin_amdgcn_s_setprio(0);
    }
  }

  // ---- epilogue ----
  float inv = 1.f / l_r;
  float* obase = out + ((size_t)bh * S_ + (size_t)(qb * 32 + w * 16 + lr)) * 64;
#pragma unroll
  for (int dt = 0; dt < 4; ++dt) {
    f32x4 ov = o_acc[dt] * inv;
    *(f32x4*)(obase + dt * 16 + 4 * lg) = ov;
  }
}

// ---------------- fallback (R1 kernel, used only if ws too small) ----------------
__launch_bounds__(256, 2)
__global__ void relattn_kernel(const float* __restrict__ qg, const float* __restrict__ kg,
                               const float* __restrict__ vg, const float* __restrict__ rel,
                               const int* __restrict__ qinfo, const int* __restrict__ kinfo,
                               float* __restrict__ out) {
  __shared__ __align__(16) unsigned short kq_lds[64 * 64];
  __shared__ __align__(16) unsigned short vt_lds[64 * 64];
  __shared__ __align__(16) unsigned short p_lds[4 * 16 * 64];
  __shared__ __align__(16) unsigned short qr_lds[64 * 272];
  __shared__ int kadj_lds[64];
  __shared__ int qadj_lds[64];
  const int t = threadIdx.x, lane = t & 63, w = t >> 6, lr = lane & 15, lg = lane >> 4;
  const int qb = blockIdx.x, bh = blockIdx.y, b = bh >> 3;
  const float* qbase = qg + ((size_t)bh * S_ + (size_t)qb * 64) * D_;
  const float* kbase = kg + (size_t)bh * S_ * D_;
  const float* vbase = vg + (size_t)bh * S_ * D_;
#pragma unroll
  for (int p = 0; p < 4; ++p) {
    int row = p * 16 + (t >> 4), col = (t & 15) * 4;
    const float4 f = *(const float4*)(qbase + row * 64 + col);
    ushort4 u = make_ushort4(f2bf(f.x), f2bf(f.y), f2bf(f.z), f2bf(f.w));
    *(ushort4*)(&kq_lds[row * 64 + (col ^ ((row & 7) << 3))]) = u;
  }
  if (t < 64) { int qa = qinfo[b * S_ + qb * 64 + t]; qadj_lds[t] = (qa == -1) ? 2 * R_ : qa; }
  __syncthreads();
  bf16x8 qa0, qa1;
  {
    const unsigned short* rbase = &kq_lds[(w * 16 + lr) * 64];
    qa0 = *(const bf16x8*)(rbase + ((8 * lg) ^ ((lr & 7) << 3)));
    qa1 = *(const bf16x8*)(rbase + ((32 + 8 * lg) ^ ((lr & 7) << 3)));
  }
  int qadj_r[4];
#pragma unroll
  for (int j = 0; j < 4; ++j) qadj_r[j] = qadj_lds[w * 16 + 4 * lg + j];
  const int qr_rowbase = (w * 16 + 4 * lg) * 272;
#pragma unroll 1
  for (int rt = 0; rt < 17; ++rt) {
    int r = rt * 16 + lr;
    u16x8 t0 = {0,0,0,0,0,0,0,0}, t1 = {0,0,0,0,0,0,0,0};
    if (r < 257) {
      const float* rp = rel + r * 64 + 8 * lg;
      float4 fa = *(const float4*)(rp), fb = *(const float4*)(rp + 4);
      float4 fc = *(const float4*)(rp + 32), fd = *(const float4*)(rp + 36);
      t0 = (u16x8){f2bf(fa.x), f2bf(fa.y), f2bf(fa.z), f2bf(fa.w), f2bf(fb.x), f2bf(fb.y), f2bf(fb.z), f2bf(fb.w)};
      t1 = (u16x8){f2bf(fc.x), f2bf(fc.y), f2bf(fc.z), f2bf(fc.w), f2bf(fd.x), f2bf(fd.y), f2bf(fd.z), f2bf(fd.w)};
    }
    bf16x8 rb0 = __builtin_bit_cast(bf16x8, t0), rb1 = __builtin_bit_cast(bf16x8, t1);
    f32x4 acc = {0.f, 0.f, 0.f, 0.f};
    acc = __builtin_amdgcn_mfma_f32_16x16x32_bf16(qa0, rb0, acc, 0, 0, 0);
    acc = __builtin_amdgcn_mfma_f32_16x16x32_bf16(qa1, rb1, acc, 0, 0, 0);
#pragma unroll
    for (int j = 0; j < 4; ++j) qr_lds[qr_rowbase + j * 272 + rt * 16 + lr] = f2bf(acc[j]);
  }
  float m_r[4], l_r[4];
  f32x4 o_acc[4];
#pragma unroll
  for (int j = 0; j < 4; ++j) { m_r[j] = -INFINITY; l_r[j] = 0.f; }
#pragma unroll
  for (int dt = 0; dt < 4; ++dt) o_acc[dt] = (f32x4){0.f, 0.f, 0.f, 0.f};
  const float SC = 0.125f * 1.44269504088896340736f;
  unsigned short* p_w = &p_lds[w * 16 * 64];
  for (int kt = 0; kt < 32; ++kt) {
    __syncthreads();
    const float* ksrc = kbase + (size_t)(kt * 64) * 64;
    const float* vsrc = vbase + (size_t)(kt * 64) * 64;
#pragma unroll
    for (int p = 0; p < 4; ++p) {
      int row = p * 16 + (t >> 4), col = (t & 15) * 4;
      float4 f = *(const float4*)(ksrc + row * 64 + col);
      ushort4 u = make_ushort4(f2bf(f.x), f2bf(f.y), f2bf(f.z), f2bf(f.w));
      *(ushort4*)(&kq_lds[row * 64 + (col ^ ((row & 7) << 3))]) = u;
      float4 fv = *(const float4*)(vsrc + row * 64 + col);
      vt_lds[(col + 0) * 64 + (row ^ (((col + 0) & 7) << 3))] = f2bf(fv.x);
      vt_lds[(col + 1) * 64 + (row ^ (((col + 1) & 7) << 3))] = f2bf(fv.y);
      vt_lds[(col + 2) * 64 + (row ^ (((col + 2) & 7) << 3))] = f2bf(fv.z);
      vt_lds[(col + 3) * 64 + (row ^ (((col + 3) & 7) << 3))] = f2bf(fv.w);
    }
    if (t < 64) { int ka = kinfo[b * S_ + kt * 64 + t]; kadj_lds[t] = (ka == -1) ? 3 * R_ : ka; }
    __syncthreads();
    f32x4 sfr[4];
#pragma unroll
    for (int st = 0; st < 4; ++st) {
      const unsigned short* kb = &kq_lds[(st * 16 + lr) * 64];
      bf16x8 kb0 = *(const bf16x8*)(kb + ((8 * lg) ^ ((lr & 7) << 3)));
      bf16x8 kb1 = *(const bf16x8*)(kb + ((32 + 8 * lg) ^ ((lr & 7) << 3)));
      f32x4 acc = {0.f, 0.f, 0.f, 0.f};
      acc = __builtin_amdgcn_mfma_f32_16x16x32_bf16(qa0, kb0, acc, 0, 0, 0);
      acc = __builtin_amdgcn_mfma_f32_16x16x32_bf16(qa1, kb1, acc, 0, 0, 0);
      sfr[st] = acc;
    }
    float tv[4][4];
#pragma unroll
    for (int st = 0; st < 4; ++st) {
      int ka = kadj_lds[st * 16 + lr];
#pragma unroll
      for (int j = 0; j < 4; ++j) {
        int dm = ka - qadj_r[j];
        dm = min(max(dm, -R_), R_) + R_;
        tv[st][j] = (sfr[st][j] + bf2f(qr_lds[qr_rowbase + j * 272 + dm])) * SC;
      }
    }
#pragma unroll
    for (int j = 0; j < 4; ++j) {
      float mx = fmaxf(fmaxf(tv[0][j], tv[1][j]), fmaxf(tv[2][j], tv[3][j]));
      mx = fmaxf(mx, __shfl_xor(mx, 1)); mx = fmaxf(mx, __shfl_xor(mx, 2));
      mx = fmaxf(mx, __shfl_xor(mx, 4)); mx = fmaxf(mx, __shfl_xor(mx, 8));
      float mnew = fmaxf(m_r[j], mx);
      float scale = exp2f(m_r[j] - mnew);
      float rs = 0.f;
#pragma unroll
      for (int st = 0; st < 4; ++st) { float p = exp2f(tv[st][j] - mnew); tv[st][j] = p; rs += p; }
      rs += __shfl_xor(rs, 1); rs += __shfl_xor(rs, 2);
      rs += __shfl_xor(rs, 4); rs += __shfl_xor(rs, 8);
      l_r[j] = l_r[j] * scale + rs;
      m_r[j] = mnew;
#pragma unroll
      for (int dt = 0; dt < 4; ++dt) o_acc[dt][j] *= scale;
    }
#pragma unroll
    for (int st = 0; st < 4; ++st)
#pragma unroll
      for (int j = 0; j < 4; ++j) {
        int row = 4 * lg + j, col = st * 16 + lr;
        p_w[row * 64 + (col ^ ((row & 7) << 3))] = f2bf(tv[st][j]);
      }
    bf16x8 pa0, pa1;
    {
      const unsigned short* pb = &p_w[lr * 64];
      pa0 = *(const bf16x8*)(pb + ((8 * lg) ^ ((lr & 7) << 3)));
      pa1 = *(const bf16x8*)(pb + ((32 + 8 * lg) ^ ((lr & 7) << 3)));
    }
#pragma unroll
    for (int dt = 0; dt < 4; ++dt) {
      const unsigned short* vb = &vt_lds[(dt * 16 + lr) * 64];
      bf16x8 vb0 = *(const bf16x8*)(vb + ((8 * lg) ^ ((lr & 7) << 3)));
      bf16x8 vb1 = *(const bf16x8*)(vb + ((32 + 8 * lg) ^ ((lr & 7) << 3)));
      o_acc[dt] = __builtin_amdgcn_mfma_f32_16x16x32_bf16(pa0, vb0, o_acc[dt], 0, 0, 0);
      o_acc[dt] = __builtin_amdgcn_mfma_f32_16x16x32_bf16(pa1, vb1, o_acc[dt], 0, 0, 0);
    }
  }
  float* obase = out + ((size_t)bh * S_ + (size_t)(qb * 64 + w * 16)) * 64;
#pragma unroll
  for (int j = 0; j < 4; ++j) {
    float inv = 1.f / l_r[j];
    int row = 4 * lg + j;
#pragma unroll
    for (int dt = 0; dt < 4; ++dt) obase[row * 64 + dt * 16 + lr] = o_acc[dt][j] * inv;
  }
}

extern "C" void kernel_launch(void* const* d_in, const int* in_sizes, int n_in,
                              void* d_out, int out_size, void* d_ws, size_t ws_size,
                              hipStream_t stream) {
  const float* q = (const float*)d_in[0];
  const float* k = (const float*)d_in[1];
  const float* v = (const float*)d_in[2];
  const float* rel = (const float*)d_in[3];
  const int* qi = (const int*)d_in[4];
  const int* ki = (const int*)d_in[5];
  float* out = (float*)d_out;

  // ws layout: kws 4MB | vws 4MB | kfix 16KB
  const size_t need = (size_t)8 * 1024 * 1024 + 16384;
  if (ws_size >= need) {
    unsigned short* kws = (unsigned short*)d_ws;
    unsigned short* vws = (unsigned short*)((char*)d_ws + 4 * 1024 * 1024);
    int* kfix = (int*)((char*)d_ws + 8 * 1024 * 1024);
    prep_kernel<<<dim3(32, 16), dim3(256), 0, stream>>>(k, v, ki, kws, vws, kfix);
    relattn4_kernel<<<dim3(64 * 16), dim3(128), SMEM4, stream>>>(q, rel, qi, kfix, kws, vws, out);
  } else {
    relattn_kernel<<<dim3(S_ / 64, B_ * H_), dim3(256), 0, stream>>>(q, k, v, rel, qi, ki, out);
  }
}